// Round 7
// baseline (241.767 us; speedup 1.0000x reference)
//
#include <hip/hip_runtime.h>
#include <math.h>

#define IN_F 4096
#define OUT_F 4096
#define BATCH 256
#define TSTEPS 8

#define BN 64
#define BK 32
#define KSPLIT 8
#define KLEN (IN_F / KSPLIT) /* 512 */
#define NKT (KLEN / BK)      /* 16 */

typedef _Float16 f16x8 __attribute__((ext_vector_type(8)));
typedef float f32x4 __attribute__((ext_vector_type(4)));

// Split one fp32 (pre-scaled x64) into two fp16 planes: v ~= h0 + h1*2^-11.
__device__ __forceinline__ void cvt8(const float4 a, const float4 b,
                                     f16x8& h0, f16x8& h1) {
  const float v[8] = {a.x, a.y, a.z, a.w, b.x, b.y, b.z, b.w};
#pragma unroll
  for (int j = 0; j < 8; ++j) {
    const float sv = v[j] * 64.0f;
    const _Float16 c0 = (_Float16)sv;
    const float r = (sv - (float)c0) * 2048.0f;
    h0[j] = c0;
    h1[j] = (_Float16)r;
  }
}

// ---------------------------------------------------------------------------
// Pre-split X (256x4096 fp32) into two fp16 planes in d_ws (4 MB total).
// ---------------------------------------------------------------------------
__global__ __launch_bounds__(256) void split_x(const float* __restrict__ X,
                                               _Float16* __restrict__ h0p,
                                               _Float16* __restrict__ h1p) {
  const size_t idx = ((size_t)blockIdx.x * 256 + threadIdx.x) * 8;
  const float4 a = *(const float4*)&X[idx];
  const float4 b = *(const float4*)&X[idx + 4];
  f16x8 h0, h1;
  cvt8(a, b, h0, h1);
  *(f16x8*)&h0p[idx] = h0;
  *(f16x8*)&h1p[idx] = h1;
}

// ---------------------------------------------------------------------------
// Barrier-free streaming fp16-split MFMA GEMM.
// Block = 512 threads (8 waves), tile 256x64, wave w owns rows w*32..+31.
// W read ONCE from HBM as fp32 fragments (per-lane 16 rows x 128B pattern),
// converted in-register; A from pre-split fp16 planes (L2/L3-resident).
// No __shared__, no __syncthreads -> no vmcnt(0) barrier drains.
// ---------------------------------------------------------------------------
template <bool USE_WS>
__global__ void gemm_stream(const _Float16* __restrict__ Ah0,
                            const _Float16* __restrict__ Ah1,
                            const float* __restrict__ X,
                            const float* __restrict__ Wt,
                            float* __restrict__ out) {
  const int tid = threadIdx.x;
  const int lane = tid & 63;
  const int w = tid >> 6;  // wave 0..7 -> rows w*32..w*32+31
  const int lr = lane & 15;
  const int lk = lane >> 4;

  const int n0 = blockIdx.x * BN;
  const int kbeg = blockIdx.z * KLEN;

  // A fragment pointers (per-lane, fp16 planes): rows w*32+{0,16}+lr
  const _Float16* pa0 = Ah0 + (size_t)(w * 32 + lr) * IN_F + kbeg + lk * 8;
  const _Float16* pa1 = Ah1 + (size_t)(w * 32 + lr) * IN_F + kbeg + lk * 8;
  // fallback: raw fp32 X fragments
  const float* pax = X + (size_t)(w * 32 + lr) * IN_F + kbeg + lk * 8;
  // B fragment base (fp32 W): row n0+j*16+lr, k-chunk lk*8
  const float* pb = Wt + (size_t)(n0 + lr) * IN_F + kbeg + lk * 8;

  f32x4 acc0[2][4], acc1[2][4];
#pragma unroll
  for (int i = 0; i < 2; ++i)
#pragma unroll
    for (int j = 0; j < 4; ++j) {
      acc0[i][j] = (f32x4){0.f, 0.f, 0.f, 0.f};
      acc1[i][j] = (f32x4){0.f, 0.f, 0.f, 0.f};
    }

#pragma unroll 4
  for (int kt = 0; kt < NKT; ++kt) {
    const int ko = kt * BK;

    f16x8 fa0[2], fa1[2];
    if (USE_WS) {
      fa0[0] = *(const f16x8*)(pa0 + ko);
      fa0[1] = *(const f16x8*)(pa0 + (size_t)16 * IN_F + ko);
      fa1[0] = *(const f16x8*)(pa1 + ko);
      fa1[1] = *(const f16x8*)(pa1 + (size_t)16 * IN_F + ko);
    } else {
      const float4 a00 = *(const float4*)(pax + ko);
      const float4 a01 = *(const float4*)(pax + ko + 4);
      const float4 a10 = *(const float4*)(pax + (size_t)16 * IN_F + ko);
      const float4 a11 = *(const float4*)(pax + (size_t)16 * IN_F + ko + 4);
      cvt8(a00, a01, fa0[0], fa1[0]);
      cvt8(a10, a11, fa0[1], fa1[1]);
    }

#pragma unroll
    for (int j = 0; j < 4; ++j) {
      const float* pbj = pb + (size_t)(j * 16) * IN_F + ko;
      const float4 b0 = *(const float4*)(pbj);
      const float4 b1 = *(const float4*)(pbj + 4);
      f16x8 fb0, fb1;
      cvt8(b0, b1, fb0, fb1);
#pragma unroll
      for (int i = 0; i < 2; ++i) {
        acc0[i][j] = __builtin_amdgcn_mfma_f32_16x16x32_f16(fa0[i], fb0, acc0[i][j], 0, 0, 0);
        acc1[i][j] = __builtin_amdgcn_mfma_f32_16x16x32_f16(fa0[i], fb1, acc1[i][j], 0, 0, 0);
        acc1[i][j] = __builtin_amdgcn_mfma_f32_16x16x32_f16(fa1[i], fb0, acc1[i][j], 0, 0, 0);
      }
    }
  }

  // epilogue: C/D layout col=lane&15, row=(lane>>4)*4+reg
#pragma unroll
  for (int i = 0; i < 2; ++i) {
    const int rbase = w * 32 + i * 16 + lk * 4;
#pragma unroll
    for (int j = 0; j < 4; ++j) {
      const int c = n0 + j * 16 + lr;
#pragma unroll
      for (int r = 0; r < 4; ++r) {
        const float val = acc0[i][j][r] * 2.44140625e-4f /* 2^-12 */ +
                          acc1[i][j][r] * 1.1920928955078125e-7f /* 2^-23 */;
        atomicAdd(&out[(size_t)(rbase + r) * OUT_F + c], val);
      }
    }
  }
}

// ---------------------------------------------------------------------------
// Fused bias + LayerNorm + tanh*|mag| + 8-step Izhikevich. 512 thr/row.
// ---------------------------------------------------------------------------
__global__ __launch_bounds__(512) void snn_fused(
    float* __restrict__ raw, const float* __restrict__ bias,
    const float* __restrict__ gamma, const float* __restrict__ beta,
    const float* __restrict__ cmag, const float* __restrict__ noise) {
  const int row = blockIdx.x;
  const int tid = threadIdx.x;
  const int lane = tid & 63;
  const int wid = tid >> 6;
  const int col = tid * 8;
  __shared__ float redS[8], redQ[8];

  float x[8];
#pragma unroll
  for (int p = 0; p < 2; ++p) {
    const float4 rv = *(const float4*)&raw[(size_t)row * OUT_F + col + p * 4];
    const float4 bv = *(const float4*)&bias[col + p * 4];
    x[p * 4 + 0] = rv.x + bv.x;
    x[p * 4 + 1] = rv.y + bv.y;
    x[p * 4 + 2] = rv.z + bv.z;
    x[p * 4 + 3] = rv.w + bv.w;
  }
  float s = 0.f, q = 0.f;
#pragma unroll
  for (int e = 0; e < 8; ++e) {
    s += x[e];
    q += x[e] * x[e];
  }
#pragma unroll
  for (int off = 32; off; off >>= 1) {
    s += __shfl_xor(s, off);
    q += __shfl_xor(q, off);
  }
  if (lane == 0) {
    redS[wid] = s;
    redQ[wid] = q;
  }
  __syncthreads();
  s = 0.f;
  q = 0.f;
#pragma unroll
  for (int wv = 0; wv < 8; ++wv) {
    s += redS[wv];
    q += redQ[wv];
  }
  const float mu = s * (1.0f / (float)OUT_F);
  const float var = q * (1.0f / (float)OUT_F) - mu * mu;
  const float sc = 1.0f / sqrtf(var + 1e-5f);
  const float mag = fabsf(cmag[0]);

  float I[8];
#pragma unroll
  for (int p = 0; p < 2; ++p) {
    const float4 g = *(const float4*)&gamma[col + p * 4];
    const float4 be = *(const float4*)&beta[col + p * 4];
    I[p * 4 + 0] = tanhf((x[p * 4 + 0] - mu) * sc * g.x + be.x) * mag;
    I[p * 4 + 1] = tanhf((x[p * 4 + 1] - mu) * sc * g.y + be.y) * mag;
    I[p * 4 + 2] = tanhf((x[p * 4 + 2] - mu) * sc * g.z + be.z) * mag;
    I[p * 4 + 3] = tanhf((x[p * 4 + 3] - mu) * sc * g.w + be.w) * mag;
  }

  float v[8], u[8];
  int cnt[8];
#pragma unroll
  for (int j = 0; j < 8; ++j) {
    v[j] = -65.0f;
    u[j] = -13.0f;
    cnt[j] = 0;
  }

#pragma unroll
  for (int t = 0; t < TSTEPS; ++t) {
    float nn[8];
#pragma unroll
    for (int p = 0; p < 2; ++p) {
      const float4 nz = *(const float4*)&noise[(((size_t)t * BATCH) + row) * OUT_F + col + p * 4];
      nn[p * 4 + 0] = nz.x;
      nn[p * 4 + 1] = nz.y;
      nn[p * 4 + 2] = nz.z;
      nn[p * 4 + 3] = nz.w;
    }
#pragma unroll
    for (int j = 0; j < 8; ++j) {
      const float It = I[j] + 0.3f * nn[j];
      const float vv = v[j];
      const float dv = (0.04f * vv * vv + 5.0f * vv + 140.0f - u[j] + It) * 0.5f;
      const float du = 0.02f * (0.2f * vv - u[j]) * 0.5f;
      float vn = vv + dv;
      vn = fminf(fmaxf(vn, -100.0f), 60.0f);
      float un = u[j] + du;
      un = fminf(fmaxf(un, -100.0f), 100.0f);
      const bool sp = (vn >= 30.0f);
      v[j] = sp ? -65.0f : vn;
      u[j] = sp ? (un + 8.0f) : un;
      cnt[j] += sp ? 1 : 0;
    }
  }

#pragma unroll
  for (int p = 0; p < 2; ++p) {
    float4 o;
    o.x = (float)cnt[p * 4 + 0] * 0.125f;
    o.y = (float)cnt[p * 4 + 1] * 0.125f;
    o.z = (float)cnt[p * 4 + 2] * 0.125f;
    o.w = (float)cnt[p * 4 + 3] * 0.125f;
    *(float4*)&raw[(size_t)row * OUT_F + col + p * 4] = o;
  }
}

extern "C" void kernel_launch(void* const* d_in, const int* in_sizes, int n_in,
                              void* d_out, int out_size, void* d_ws, size_t ws_size,
                              hipStream_t stream) {
  const float* x = (const float*)d_in[0];
  const float* W = (const float*)d_in[1];
  const float* b = (const float*)d_in[2];
  const float* gam = (const float*)d_in[3];
  const float* bet = (const float*)d_in[4];
  const float* cmag = (const float*)d_in[5];
  const float* nz = (const float*)d_in[6];
  float* out = (float*)d_out;

  // d_out doubles as the raw-GEMM accumulator (split-K atomics need zeros)
  hipMemsetAsync(out, 0, (size_t)BATCH * OUT_F * sizeof(float), stream);

  const size_t plane_elems = (size_t)BATCH * IN_F;
  const bool use_ws = ws_size >= 2 * plane_elems * sizeof(_Float16);

  dim3 grid1(OUT_F / BN, 1, KSPLIT);
  if (use_ws) {
    _Float16* ah0 = (_Float16*)d_ws;
    _Float16* ah1 = ah0 + plane_elems;
    split_x<<<plane_elems / (256 * 8), 256, 0, stream>>>(x, ah0, ah1);
    gemm_stream<true><<<grid1, 512, 0, stream>>>(ah0, ah1, x, W, out);
  } else {
    gemm_stream<false><<<grid1, 512, 0, stream>>>(nullptr, nullptr, x, W, out);
  }

  snn_fused<<<BATCH, 512, 0, stream>>>(out, b, gam, bet, cmag, nz);
}

// Round 8
// 205.392 us; speedup vs baseline: 1.1771x; 1.1771x over previous
//
#include <hip/hip_runtime.h>
#include <math.h>

#define IN_F 4096
#define OUT_F 4096
#define BATCH 256
#define TSTEPS 8

#define KSPLIT 8
#define KLEN (IN_F / KSPLIT) /* 512 */

typedef _Float16 f16x8 __attribute__((ext_vector_type(8)));
typedef float f32x4 __attribute__((ext_vector_type(4)));

// Split one fp32 (pre-scaled x64) into two fp16 planes: v ~= (h0 + h1*2^-11)/64.
__device__ __forceinline__ void cvt8(const float4 a, const float4 b,
                                     f16x8& h0, f16x8& h1) {
  const float v[8] = {a.x, a.y, a.z, a.w, b.x, b.y, b.z, b.w};
#pragma unroll
  for (int j = 0; j < 8; ++j) {
    const float sv = v[j] * 64.0f;
    const _Float16 c0 = (_Float16)sv;
    const float r = (sv - (float)c0) * 2048.0f;
    h0[j] = c0;
    h1[j] = (_Float16)r;
  }
}

// ---------------------------------------------------------------------------
// Persistent-accumulator fp16-split MFMA GEMM.
// 256 blocks = 32 n-blocks (BN=128) x KSPLIT=8 (k-slice 512).
// BM=256 (all of M): W is read exactly once from HBM chip-wide.
// A k-slice staged in 8 sub-stages of 64k into 64KB LDS (2 fp16 planes,
// XOR-swizzled). acc[4][4] x 2 planes persists across sub-stages ->
// one atomicAdd per output per block (8.4M total, proven scale).
// 8 waves = 4 m-quads x 2 n-groups. A prefetched one stage ahead,
// W prefetched one j-tile ahead.
// ---------------------------------------------------------------------------
__global__ __launch_bounds__(512, 2) void gemm_fused(
    const float* __restrict__ X, const float* __restrict__ Wt,
    float* __restrict__ out) {
  __shared__ __align__(16) char Al[65536];  // [plane 2][row 256][64 fp16]

  const int tid = threadIdx.x;
  const int lane = tid & 63;
  const int w = tid >> 6;
  const int mq = w & 3;   // m-quad: rows mq*64..+63
  const int ng = w >> 2;  // n-group: cols ng*64..+63 within block tile
  const int lr = lane & 15;
  const int lk = lane >> 4;

  const int nb = blockIdx.x & 31;
  const int ksl = blockIdx.x >> 5;
  const int n0 = nb * 128;
  const int kbeg = ksl * KLEN;

  // A staging: thread owns row tid>>1, k-half (tid&1)*32 of each 64-k stage
  const int srow = tid >> 1;
  const int skh = (tid & 1) * 32;
  const float* px = X + (size_t)srow * IN_F + kbeg + skh;

  // W fragments: col-row n0+ng*64+jt*16+lr, k-chunk lk*8
  const float* pw = Wt + (size_t)(n0 + ng * 64 + lr) * IN_F + kbeg + lk * 8;

  f32x4 acc0[4][4], acc1[4][4];
#pragma unroll
  for (int i = 0; i < 4; ++i)
#pragma unroll
    for (int j = 0; j < 4; ++j) {
      acc0[i][j] = (f32x4){0.f, 0.f, 0.f, 0.f};
      acc1[i][j] = (f32x4){0.f, 0.f, 0.f, 0.f};
    }

  // prologue: A prefetch for st=0
  float4 Apre[8];
#pragma unroll
  for (int c = 0; c < 8; ++c) Apre[c] = *(const float4*)(px + c * 4);

#define LOADW2(P, JT) \
  do { \
    P[0] = *(const float4*)(pwst + (size_t)(JT) * 16 * IN_F); \
    P[1] = *(const float4*)(pwst + (size_t)(JT) * 16 * IN_F + 4); \
  } while (0)

#define COMPUTE2(P, JT) \
  do { \
    f16x8 fb0, fb1; \
    cvt8(P[0], P[1], fb0, fb1); \
    _Pragma("unroll") for (int i_ = 0; i_ < 4; ++i_) { \
      acc0[i_][JT] = __builtin_amdgcn_mfma_f32_16x16x32_f16(fa0[i_], fb0, acc0[i_][JT], 0, 0, 0); \
      acc1[i_][JT] = __builtin_amdgcn_mfma_f32_16x16x32_f16(fa0[i_], fb1, acc1[i_][JT], 0, 0, 0); \
      acc1[i_][JT] = __builtin_amdgcn_mfma_f32_16x16x32_f16(fa1[i_], fb0, acc1[i_][JT], 0, 0, 0); \
    } \
  } while (0)

  for (int st = 0; st < 8; ++st) {
    __syncthreads();  // all reads of previous stage done
    // stage A planes from prefetched regs (cvt + swizzled ds_write)
#pragma unroll
    for (int c = 0; c < 4; ++c) {
      f16x8 h0, h1;
      cvt8(Apre[2 * c], Apre[2 * c + 1], h0, h1);
      const int boff = (skh * 2 + c * 16) ^ ((srow & 7) << 4);
      *(f16x8*)(Al + (size_t)srow * 128 + boff) = h0;
      *(f16x8*)(Al + 32768 + (size_t)srow * 128 + boff) = h1;
    }
    __syncthreads();

#pragma unroll
    for (int ks = 0; ks < 2; ++ks) {
      // A fragments for this 32-k chunk (swizzled LDS reads)
      f16x8 fa0[4], fa1[4];
#pragma unroll
      for (int i = 0; i < 4; ++i) {
        const int row = mq * 64 + i * 16 + lr;
        const int boff = (ks * 64 + lk * 16) ^ ((row & 7) << 4);
        fa0[i] = *(const f16x8*)(Al + (size_t)row * 128 + boff);
        fa1[i] = *(const f16x8*)(Al + 32768 + (size_t)row * 128 + boff);
      }
      // A prefetch for next stage (issued mid-stage, hides HBM/L2 latency)
      if (ks == 1 && st < 7) {
        const float* pxn = px + (st + 1) * 64;
#pragma unroll
        for (int c = 0; c < 8; ++c) Apre[c] = *(const float4*)(pxn + c * 4);
      }

      const float* pwst = pw + st * 64 + ks * 32;
      float4 p0[2], p1[2];
      LOADW2(p0, 0);
      LOADW2(p1, 1);
      COMPUTE2(p0, 0);
      LOADW2(p0, 2);
      COMPUTE2(p1, 1);
      LOADW2(p1, 3);
      COMPUTE2(p0, 2);
      COMPUTE2(p1, 3);
    }
  }

  // epilogue: C/D layout col=lane&15, row=(lane>>4)*4+reg; one atomic/output
  const int cbase = n0 + ng * 64 + lr;
#pragma unroll
  for (int i = 0; i < 4; ++i) {
    const int rbase = mq * 64 + i * 16 + lk * 4;
#pragma unroll
    for (int jt = 0; jt < 4; ++jt) {
      const int c = cbase + jt * 16;
#pragma unroll
      for (int r = 0; r < 4; ++r) {
        const float val = acc0[i][jt][r] * 2.44140625e-4f /* 2^-12 */ +
                          acc1[i][jt][r] * 1.1920928955078125e-7f /* 2^-23 */;
        atomicAdd(&out[(size_t)(rbase + r) * OUT_F + c], val);
      }
    }
  }
#undef LOADW2
#undef COMPUTE2
}

// ---------------------------------------------------------------------------
// Fused bias + LayerNorm + tanh*|mag| + 8-step Izhikevich. 512 thr/row.
// Single-pass sum/sumsq reduction (E[x^2]-mu^2).
// ---------------------------------------------------------------------------
__global__ __launch_bounds__(512) void snn_fused(
    float* __restrict__ raw, const float* __restrict__ bias,
    const float* __restrict__ gamma, const float* __restrict__ beta,
    const float* __restrict__ cmag, const float* __restrict__ noise) {
  const int row = blockIdx.x;
  const int tid = threadIdx.x;
  const int lane = tid & 63;
  const int wid = tid >> 6;
  const int col = tid * 8;
  __shared__ float redS[8], redQ[8];

  float x[8];
#pragma unroll
  for (int p = 0; p < 2; ++p) {
    const float4 rv = *(const float4*)&raw[(size_t)row * OUT_F + col + p * 4];
    const float4 bv = *(const float4*)&bias[col + p * 4];
    x[p * 4 + 0] = rv.x + bv.x;
    x[p * 4 + 1] = rv.y + bv.y;
    x[p * 4 + 2] = rv.z + bv.z;
    x[p * 4 + 3] = rv.w + bv.w;
  }
  float s = 0.f, q = 0.f;
#pragma unroll
  for (int e = 0; e < 8; ++e) {
    s += x[e];
    q += x[e] * x[e];
  }
#pragma unroll
  for (int off = 32; off; off >>= 1) {
    s += __shfl_xor(s, off);
    q += __shfl_xor(q, off);
  }
  if (lane == 0) {
    redS[wid] = s;
    redQ[wid] = q;
  }
  __syncthreads();
  s = 0.f;
  q = 0.f;
#pragma unroll
  for (int wv = 0; wv < 8; ++wv) {
    s += redS[wv];
    q += redQ[wv];
  }
  const float mu = s * (1.0f / (float)OUT_F);
  const float var = q * (1.0f / (float)OUT_F) - mu * mu;
  const float sc = 1.0f / sqrtf(var + 1e-5f);
  const float mag = fabsf(cmag[0]);

  float I[8];
#pragma unroll
  for (int p = 0; p < 2; ++p) {
    const float4 g = *(const float4*)&gamma[col + p * 4];
    const float4 be = *(const float4*)&beta[col + p * 4];
    I[p * 4 + 0] = tanhf((x[p * 4 + 0] - mu) * sc * g.x + be.x) * mag;
    I[p * 4 + 1] = tanhf((x[p * 4 + 1] - mu) * sc * g.y + be.y) * mag;
    I[p * 4 + 2] = tanhf((x[p * 4 + 2] - mu) * sc * g.z + be.z) * mag;
    I[p * 4 + 3] = tanhf((x[p * 4 + 3] - mu) * sc * g.w + be.w) * mag;
  }

  float v[8], u[8];
  int cnt[8];
#pragma unroll
  for (int j = 0; j < 8; ++j) {
    v[j] = -65.0f;
    u[j] = -13.0f;
    cnt[j] = 0;
  }

#pragma unroll
  for (int t = 0; t < TSTEPS; ++t) {
    float nn[8];
#pragma unroll
    for (int p = 0; p < 2; ++p) {
      const float4 nz = *(const float4*)&noise[(((size_t)t * BATCH) + row) * OUT_F + col + p * 4];
      nn[p * 4 + 0] = nz.x;
      nn[p * 4 + 1] = nz.y;
      nn[p * 4 + 2] = nz.z;
      nn[p * 4 + 3] = nz.w;
    }
#pragma unroll
    for (int j = 0; j < 8; ++j) {
      const float It = I[j] + 0.3f * nn[j];
      const float vv = v[j];
      const float dv = (0.04f * vv * vv + 5.0f * vv + 140.0f - u[j] + It) * 0.5f;
      const float du = 0.02f * (0.2f * vv - u[j]) * 0.5f;
      float vn = vv + dv;
      vn = fminf(fmaxf(vn, -100.0f), 60.0f);
      float un = u[j] + du;
      un = fminf(fmaxf(un, -100.0f), 100.0f);
      const bool sp = (vn >= 30.0f);
      v[j] = sp ? -65.0f : vn;
      u[j] = sp ? (un + 8.0f) : un;
      cnt[j] += sp ? 1 : 0;
    }
  }

#pragma unroll
  for (int p = 0; p < 2; ++p) {
    float4 o;
    o.x = (float)cnt[p * 4 + 0] * 0.125f;
    o.y = (float)cnt[p * 4 + 1] * 0.125f;
    o.z = (float)cnt[p * 4 + 2] * 0.125f;
    o.w = (float)cnt[p * 4 + 3] * 0.125f;
    *(float4*)&raw[(size_t)row * OUT_F + col + p * 4] = o;
  }
}

extern "C" void kernel_launch(void* const* d_in, const int* in_sizes, int n_in,
                              void* d_out, int out_size, void* d_ws, size_t ws_size,
                              hipStream_t stream) {
  const float* x = (const float*)d_in[0];
  const float* W = (const float*)d_in[1];
  const float* b = (const float*)d_in[2];
  const float* gam = (const float*)d_in[3];
  const float* bet = (const float*)d_in[4];
  const float* cmag = (const float*)d_in[5];
  const float* nz = (const float*)d_in[6];
  float* out = (float*)d_out;
  (void)d_ws;
  (void)ws_size;

  // d_out doubles as the raw-GEMM accumulator (split-K atomics need zeros)
  hipMemsetAsync(out, 0, (size_t)BATCH * OUT_F * sizeof(float), stream);

  gemm_fused<<<256, 512, 0, stream>>>(x, W, out);

  snn_fused<<<BATCH, 512, 0, stream>>>(out, b, gam, bet, cmag, nz);
}